// Round 15
// baseline (1000.417 us; speedup 1.0000x reference)
//
#include <hip/hip_runtime.h>

#define N_NODES 50000
#define N_EDGES 800000

typedef __attribute__((ext_vector_type(8))) short bf16x8;
typedef __attribute__((ext_vector_type(4))) float f32x4;
typedef __attribute__((ext_vector_type(2))) float f32x2;
typedef __attribute__((ext_vector_type(4))) unsigned int u32x4;

__device__ __forceinline__ float bf2f(unsigned int u) {
  union { unsigned int u; float f; } c; c.u = (u & 0xffffu) << 16; return c.f;
}
__device__ __forceinline__ unsigned short f2bf(float f) {
  union { float f; unsigned int u; } c; c.f = f;
  return (unsigned short)((c.u + 0x8000u) >> 16);
}
// RNE packed f32x2 -> 2xbf16 in one VALU op
__device__ __forceinline__ unsigned int pk_bf16(float lo, float hi) {
  unsigned int r;
  asm("v_cvt_pk_bf16_f32 %0, %1, %2" : "=v"(r) : "v"(lo), "v"(hi));
  return r;
}

#if __has_builtin(__builtin_amdgcn_exp2f) && __has_builtin(__builtin_amdgcn_logf)
__device__ __forceinline__ float sspf(float x) {
  const float e = __builtin_amdgcn_exp2f(fabsf(x) * -1.44269504088896f);
  const float l = __builtin_amdgcn_logf(1.0f + e);
  return fmaf(0.69314718055994531f, l, fmaxf(x, 0.0f) - 0.69314718055994531f);
}
#else
__device__ __forceinline__ float sspf(float x) {
  return fmaxf(x, 0.0f) + __logf(1.0f + __expf(-fabsf(x))) - 0.69314718055994531f;
}
#endif

__device__ __forceinline__ f32x4 MFMA(bf16x8 a, bf16x8 b, f32x4 c) {
  return __builtin_amdgcn_mfma_f32_16x16x32_bf16(a, b, c, 0, 0, 0);
}
__device__ __forceinline__ f32x4 f4bcast(float v) {
  f32x4 z = {v, v, v, v}; return z;
}

__device__ __forceinline__ bf16x8 cvt8pk(const float* __restrict__ p) {
  f32x4 x0 = *(const f32x4*)p;
  f32x4 x1 = *(const f32x4*)(p + 4);
  union { u32x4 u; bf16x8 v; } r;
  r.u[0] = pk_bf16(x0[0], x0[1]);
  r.u[1] = pk_bf16(x0[2], x0[3]);
  r.u[2] = pk_bf16(x1[0], x1[1]);
  r.u[3] = pk_bf16(x1[2], x1[3]);
  return r.v;
}

// gather one 8-elem octet of eattr[perm[e0+gr]] as bf16x8 (0-padded k>=50)
__device__ __forceinline__ bf16x8 gather_ea(
    const float* __restrict__ eattr, const int* __restrict__ perm,
    int e0, int gr, int goc)
{
  const int p = perm[e0 + gr];
  const float* ap = eattr + (size_t)p * 50 + goc * 8;
  union { u32x4 u; bf16x8 v; } t;
  if (goc < 6) {
    f32x2 a0 = *(const f32x2*)(ap);
    f32x2 a1 = *(const f32x2*)(ap + 2);
    f32x2 a2 = *(const f32x2*)(ap + 4);
    f32x2 a3 = *(const f32x2*)(ap + 6);
    t.u[0] = pk_bf16(a0[0], a0[1]);
    t.u[1] = pk_bf16(a1[0], a1[1]);
    t.u[2] = pk_bf16(a2[0], a2[1]);
    t.u[3] = pk_bf16(a3[0], a3[1]);
  } else if (goc == 6) {
    f32x2 a0 = *(const f32x2*)(ap);
    t.u[0] = pk_bf16(a0[0], a0[1]);
    t.u[1] = 0; t.u[2] = 0; t.u[3] = 0;
  } else {
    t.u[0] = 0; t.u[1] = 0; t.u[2] = 0; t.u[3] = 0;
  }
  return t.v;
}

// ---------------------------------------------------------------------------
// Node GEMM: Out[M,256] = act(A@W + bias). 512 thr / 8 waves, wave owns 32
// cols. A staged once to swizzled bf16 LDS. Bias pre-loaded into acc.
// ---------------------------------------------------------------------------
template<int ADT, int ACT, int ODT>
__global__ __launch_bounds__(512, 8) void gemm512(
    const void* __restrict__ Av, const unsigned short* __restrict__ Wt,
    const float* __restrict__ bias, void* __restrict__ Outv, int M)
{
  __shared__ unsigned short a_lds[64 * 256];  // 32 KiB, swizzled
  const int m0  = (int)blockIdx.x * 64;
  const int tid = (int)threadIdx.x;

  {
    const int r   = tid >> 3;
    const int oc8 = tid & 7;
    int row = m0 + r;
    if (row >= M) row = M - 1;
    if (ADT == 1) {
      const float* ap = (const float*)Av + (size_t)row * 256 + oc8 * 32;
#pragma unroll
      for (int q = 0; q < 4; ++q) {
        const bf16x8 v = cvt8pk(ap + q * 8);
        const int byt = r * 512 + ((oc8 * 64 + q * 16) ^ ((r & 7) << 4));
        *(bf16x8*)((char*)a_lds + byt) = v;
      }
    } else {
      const unsigned short* ap =
          (const unsigned short*)Av + (size_t)row * 256 + oc8 * 32;
#pragma unroll
      for (int q = 0; q < 4; ++q) {
        const bf16x8 v = *(const bf16x8*)(ap + q * 8);
        const int byt = r * 512 + ((oc8 * 64 + q * 16) ^ ((r & 7) << 4));
        *(bf16x8*)((char*)a_lds + byt) = v;
      }
    }
  }
  __syncthreads();

  const int w  = tid >> 6, l = tid & 63, lr = l & 15, g = l >> 4;
  const int c0 = w * 32;
  const int P45 = (lr & 3) << 4;
  const int P6  = (lr & 4) << 4;
  const int alb = lr * 512 + ((g * 16) ^ P45);

  const float bs0 = bias[c0 + lr];
  const float bs1 = bias[c0 + 16 + lr];
  f32x4 acc[4][2];
#pragma unroll
  for (int a = 0; a < 4; ++a) {
    acc[a][0] = f4bcast(bs0);
    acc[a][1] = f4bcast(bs1);
  }

#pragma unroll
  for (int ks = 0; ks < 8; ++ks) {
    const int kb = ks * 32 + g * 8;
    const bf16x8 bfr0 = *(const bf16x8*)(Wt + (size_t)(c0 + lr) * 256 + kb);
    const bf16x8 bfr1 = *(const bf16x8*)(Wt + (size_t)(c0 + 16 + lr) * 256 + kb);
    const char* abase = (const char*)a_lds + (alb + ((ks * 64) ^ P6));
#pragma unroll
    for (int mf = 0; mf < 4; ++mf) {
      const bf16x8 af = *(const bf16x8*)(abase + mf * 8192);
      __builtin_amdgcn_s_setprio(1);
      acc[mf][0] = MFMA(af, bfr0, acc[mf][0]);
      acc[mf][1] = MFMA(af, bfr1, acc[mf][1]);
      __builtin_amdgcn_s_setprio(0);
    }
  }

#pragma unroll
  for (int nf = 0; nf < 2; ++nf) {
    const int col = c0 + nf * 16 + lr;
#pragma unroll
    for (int mf = 0; mf < 4; ++mf) {
#pragma unroll
      for (int i = 0; i < 4; ++i) {
        const int row = m0 + mf * 16 + g * 4 + i;
        if (row < M) {
          float x = acc[mf][nf][i];
          if (ACT) x = sspf(x);
          if (ODT == 0)
            ((unsigned short*)Outv)[(size_t)row * 256 + col] = f2bf(x);
          else
            ((float*)Outv)[(size_t)row * 256 + col] = x;
        }
      }
    }
  }
}

// ---------------------------------------------------------------------------
// Fused output MLP: out = ssp(agg@o1+b1)@o2+b2. Two K=256 stages on one
// 64-row tile; intermediate never leaves LDS.
// ---------------------------------------------------------------------------
__global__ __launch_bounds__(512, 8) void out_fused512(
    const float* __restrict__ agg,
    const unsigned short* __restrict__ o1t, const float* __restrict__ o1b,
    const unsigned short* __restrict__ o2t, const float* __restrict__ o2b,
    float* __restrict__ Out, int M)
{
  __shared__ unsigned short t_lds[64 * 256];  // 32 KiB; agg-tile, then o-tile
  const int m0  = (int)blockIdx.x * 64;
  const int tid = (int)threadIdx.x;

  // phase 0: stage agg -> bf16 swizzled LDS
  {
    const int r   = tid >> 3;
    const int oc8 = tid & 7;
    int row = m0 + r;
    if (row >= M) row = M - 1;
    const float* ap = agg + (size_t)row * 256 + oc8 * 32;
#pragma unroll
    for (int q = 0; q < 4; ++q) {
      const bf16x8 v = cvt8pk(ap + q * 8);
      const int byt = r * 512 + ((oc8 * 64 + q * 16) ^ ((r & 7) << 4));
      *(bf16x8*)((char*)t_lds + byt) = v;
    }
  }
  __syncthreads();

  const int w  = tid >> 6, l = tid & 63, lr = l & 15, g = l >> 4;
  const int c0 = w * 32;
  const int P45 = (lr & 3) << 4;
  const int P6  = (lr & 4) << 4;
  const int alb = lr * 512 + ((g * 16) ^ P45);

  f32x4 acc[4][2];
  {
    const float b0 = o1b[c0 + lr];
    const float b1 = o1b[c0 + 16 + lr];
#pragma unroll
    for (int a = 0; a < 4; ++a) {
      acc[a][0] = f4bcast(b0);
      acc[a][1] = f4bcast(b1);
    }
  }

  // stage 1: K=256 with o1
#pragma unroll
  for (int ks = 0; ks < 8; ++ks) {
    const int kb = ks * 32 + g * 8;
    const bf16x8 bfr0 = *(const bf16x8*)(o1t + (size_t)(c0 + lr) * 256 + kb);
    const bf16x8 bfr1 = *(const bf16x8*)(o1t + (size_t)(c0 + 16 + lr) * 256 + kb);
    const char* abase = (const char*)t_lds + (alb + ((ks * 64) ^ P6));
#pragma unroll
    for (int mf = 0; mf < 4; ++mf) {
      const bf16x8 af = *(const bf16x8*)(abase + mf * 8192);
      __builtin_amdgcn_s_setprio(1);
      acc[mf][0] = MFMA(af, bfr0, acc[mf][0]);
      acc[mf][1] = MFMA(af, bfr1, acc[mf][1]);
      __builtin_amdgcn_s_setprio(0);
    }
  }
  __syncthreads();   // stage-1 reads done before overwrite

  // epilogue 1: o = ssp(acc) -> t_lds (cvt_pk)
#pragma unroll
  for (int nf = 0; nf < 2; ++nf) {
    const int colb = (c0 + nf * 16 + lr) * 2;
#pragma unroll
    for (int i = 0; i < 4; ++i) {
      const int gi = g * 4 + i;
      char* wp = (char*)t_lds + (gi * 512 + (colb ^ ((gi & 7) << 4)));
      const float v0 = sspf(acc[0][nf][i]);
      const float v1 = sspf(acc[1][nf][i]);
      const float v2 = sspf(acc[2][nf][i]);
      const float v3 = sspf(acc[3][nf][i]);
      const unsigned int p01 = pk_bf16(v0, v1);
      const unsigned int p23 = pk_bf16(v2, v3);
      *(unsigned short*)(wp)         = (unsigned short)p01;
      *(unsigned short*)(wp + 8192)  = (unsigned short)(p01 >> 16);
      *(unsigned short*)(wp + 16384) = (unsigned short)p23;
      *(unsigned short*)(wp + 24576) = (unsigned short)(p23 >> 16);
    }
  }
  __syncthreads();

  // stage 2: K=256 with o2
  {
    const float b0 = o2b[c0 + lr];
    const float b1 = o2b[c0 + 16 + lr];
#pragma unroll
    for (int a = 0; a < 4; ++a) {
      acc[a][0] = f4bcast(b0);
      acc[a][1] = f4bcast(b1);
    }
  }
#pragma unroll
  for (int ks = 0; ks < 8; ++ks) {
    const int kb = ks * 32 + g * 8;
    const bf16x8 bfr0 = *(const bf16x8*)(o2t + (size_t)(c0 + lr) * 256 + kb);
    const bf16x8 bfr1 = *(const bf16x8*)(o2t + (size_t)(c0 + 16 + lr) * 256 + kb);
    const char* abase = (const char*)t_lds + (alb + ((ks * 64) ^ P6));
#pragma unroll
    for (int mf = 0; mf < 4; ++mf) {
      const bf16x8 af = *(const bf16x8*)(abase + mf * 8192);
      __builtin_amdgcn_s_setprio(1);
      acc[mf][0] = MFMA(af, bfr0, acc[mf][0]);
      acc[mf][1] = MFMA(af, bfr1, acc[mf][1]);
      __builtin_amdgcn_s_setprio(0);
    }
  }

  // epilogue: f32 store
#pragma unroll
  for (int nf = 0; nf < 2; ++nf) {
    const int col = c0 + nf * 16 + lr;
#pragma unroll
    for (int mf = 0; mf < 4; ++mf) {
#pragma unroll
      for (int i = 0; i < 4; ++i) {
        const int row = m0 + mf * 16 + g * 4 + i;
        if (row < M)
          Out[(size_t)row * 256 + col] = acc[mf][nf][i];
      }
    }
  }
}

// ---------------------------------------------------------------------------
// Counting sort by dst.
// ---------------------------------------------------------------------------
__global__ __launch_bounds__(256) void hist_dst(const int* __restrict__ eidx,
                                                int* __restrict__ cnt)
{
  const int e = (int)blockIdx.x * 256 + (int)threadIdx.x;
  atomicAdd(&cnt[eidx[N_EDGES + e]], 1);
}

__global__ __launch_bounds__(1024) void scan_cnt(const int* __restrict__ cnt,
                                                 int* __restrict__ cursor)
{
  __shared__ int part[1024];
  const int t = (int)threadIdx.x;
  const int base = t * 49;
  int s = 0;
#pragma unroll 7
  for (int j = 0; j < 49; ++j) {
    const int idx = base + j;
    if (idx < N_NODES) s += cnt[idx];
  }
  part[t] = s;
  __syncthreads();
  for (int off = 1; off < 1024; off <<= 1) {
    int v = 0;
    if (t >= off) v = part[t - off];
    __syncthreads();
    part[t] += v;
    __syncthreads();
  }
  int run = (t == 0) ? 0 : part[t - 1];
#pragma unroll 7
  for (int j = 0; j < 49; ++j) {
    const int idx = base + j;
    if (idx < N_NODES) { cursor[idx] = run; run += cnt[idx]; }
  }
}

__global__ __launch_bounds__(256) void scatter_perm(
    const int* __restrict__ eidx, const float* __restrict__ ew,
    int* __restrict__ cursor, int* __restrict__ perm,
    float* __restrict__ Cf, int* __restrict__ srcs, int* __restrict__ dsts)
{
  const int e = (int)blockIdx.x * 256 + (int)threadIdx.x;
  const int d = eidx[N_EDGES + e];
  const int pos = atomicAdd(&cursor[d], 1);
  perm[pos] = e;
  Cf[pos]   = 0.5f * (__cosf(ew[e] * 0.31415926535897931f) + 1.0f);
  srcs[pos] = eidx[e];
  dsts[pos] = d;
}

// ---------------------------------------------------------------------------
// FUSED edge pipeline over dst-SORTED edges. R15: each block processes TWO
// 64-edge tiles; tile-B's eattr gather + meta are issued into REGISTERS
// right after tile-A's stage-2 MFMAs (T14 async-stage: latency hides under
// ep2(A)+reduce(A)); LDS write of tile B happens after the post-reduce
// barrier. Reduce = exact R12 form (interleaved h1 gather, pure atomics).
// ---------------------------------------------------------------------------
__global__ __launch_bounds__(512, 8) void edge_fused512(
    const float* __restrict__ eattr, const int* __restrict__ perm,
    const float* __restrict__ Cf,
    const int* __restrict__ srcs, const int* __restrict__ dsts,
    const unsigned short* __restrict__ m1t, const float* __restrict__ m1b,
    const unsigned short* __restrict__ m2t, const float* __restrict__ m2b,
    const unsigned short* __restrict__ h1, float* __restrict__ agg)
{
  __shared__ unsigned short t_lds[64 * 256];  // 32 KiB; ea-tile, t, then Wf
  __shared__ float Cs[64];
  __shared__ int s_src[64];
  __shared__ int s_dst[65];
  unsigned short* ea_lds = t_lds;             // [64 rows][128B] alias (8 KiB)

  const int tid = (int)threadIdx.x;
  const int e0A = (int)blockIdx.x * 128;
  const int e0B = e0A + 64;

  // gather thread-coords (same mapping both tiles)
  const int gr   = tid >> 3;
  const int goc  = tid & 7;
  const int gbyt = gr * 128 + ((goc * 16) ^ ((gr & 7) << 4));

  // lane constants
  const int w  = tid >> 6;
  const int l  = tid & 63;
  const int lr = l & 15;
  const int g  = l >> 4;
  const int c0 = w * 32;
  const int P45  = (lr & 3) << 4;
  const int P6   = (lr & 4) << 4;
  const int alb1 = lr * 128 + ((g * 16) ^ P45);
  const int alb2 = lr * 512 + ((g * 16) ^ P45);
  const float b10 = m1b[c0 + lr];
  const float b11 = m1b[c0 + 16 + lr];
  const float b20 = m2b[c0 + lr];
  const float b21 = m2b[c0 + 16 + lr];

  // reduce thread-coords
  const int q2 = tid >> 7;
  const int cp = (tid & 127) * 2;
  const int rb = q2 * 16;

  f32x4 acc[4][2];

  // ---- per-tile phases (all-constant indices after unroll) ----
  auto stage1 = [&]() {
#pragma unroll
    for (int a = 0; a < 4; ++a) {
      acc[a][0] = f4bcast(b10);
      acc[a][1] = f4bcast(b11);
    }
#pragma unroll
    for (int ks = 0; ks < 2; ++ks) {
      const int kb = ks * 32 + g * 8;
      const bf16x8 bfr0 = *(const bf16x8*)(m1t + (c0 + lr) * 64 + kb);
      const bf16x8 bfr1 = *(const bf16x8*)(m1t + (c0 + 16 + lr) * 64 + kb);
      const char* abase = (const char*)ea_lds + (alb1 + ((ks * 64) ^ P6));
#pragma unroll
      for (int mf = 0; mf < 4; ++mf) {
        const bf16x8 af = *(const bf16x8*)(abase + mf * 2048);
        __builtin_amdgcn_s_setprio(1);
        acc[mf][0] = MFMA(af, bfr0, acc[mf][0]);
        acc[mf][1] = MFMA(af, bfr1, acc[mf][1]);
        __builtin_amdgcn_s_setprio(0);
      }
    }
  };

  auto ep1 = [&]() {
#pragma unroll
    for (int nf = 0; nf < 2; ++nf) {
      const int colb = (c0 + nf * 16 + lr) * 2;
#pragma unroll
      for (int i = 0; i < 4; ++i) {
        const int gi = g * 4 + i;
        char* wp = (char*)t_lds + (gi * 512 + (colb ^ ((gi & 7) << 4)));
        const float v0 = sspf(acc[0][nf][i]);
        const float v1 = sspf(acc[1][nf][i]);
        const float v2 = sspf(acc[2][nf][i]);
        const float v3 = sspf(acc[3][nf][i]);
        const unsigned int p01 = pk_bf16(v0, v1);
        const unsigned int p23 = pk_bf16(v2, v3);
        *(unsigned short*)(wp)         = (unsigned short)p01;
        *(unsigned short*)(wp + 8192)  = (unsigned short)(p01 >> 16);
        *(unsigned short*)(wp + 16384) = (unsigned short)p23;
        *(unsigned short*)(wp + 24576) = (unsigned short)(p23 >> 16);
      }
    }
  };

  auto stage2 = [&]() {
#pragma unroll
    for (int a = 0; a < 4; ++a) {
      acc[a][0] = f4bcast(b20);
      acc[a][1] = f4bcast(b21);
    }
#pragma unroll
    for (int ks = 0; ks < 8; ++ks) {
      const int kb = ks * 32 + g * 8;
      const bf16x8 bfr0 = *(const bf16x8*)(m2t + (size_t)(c0 + lr) * 256 + kb);
      const bf16x8 bfr1 = *(const bf16x8*)(m2t + (size_t)(c0 + 16 + lr) * 256 + kb);
      const char* abase = (const char*)t_lds + (alb2 + ((ks * 64) ^ P6));
#pragma unroll
      for (int mf = 0; mf < 4; ++mf) {
        const bf16x8 af = *(const bf16x8*)(abase + mf * 8192);
        __builtin_amdgcn_s_setprio(1);
        acc[mf][0] = MFMA(af, bfr0, acc[mf][0]);
        acc[mf][1] = MFMA(af, bfr1, acc[mf][1]);
        __builtin_amdgcn_s_setprio(0);
      }
    }
  };

  auto ep2 = [&]() {
#pragma unroll
    for (int nf = 0; nf < 2; ++nf) {
      const int colb = (c0 + nf * 16 + lr) * 2;
#pragma unroll
      for (int i = 0; i < 4; ++i) {
        const int gi = g * 4 + i;
        char* wp = (char*)t_lds + (gi * 512 + (colb ^ ((gi & 7) << 4)));
        const float v0 = sspf(acc[0][nf][i]) * Cs[gi];
        const float v1 = sspf(acc[1][nf][i]) * Cs[16 + gi];
        const float v2 = sspf(acc[2][nf][i]) * Cs[32 + gi];
        const float v3 = sspf(acc[3][nf][i]) * Cs[48 + gi];
        const unsigned int p01 = pk_bf16(v0, v1);
        const unsigned int p23 = pk_bf16(v2, v3);
        *(unsigned short*)(wp)         = (unsigned short)p01;
        *(unsigned short*)(wp + 8192)  = (unsigned short)(p01 >> 16);
        *(unsigned short*)(wp + 16384) = (unsigned short)p23;
        *(unsigned short*)(wp + 24576) = (unsigned short)(p23 >> 16);
      }
    }
  };

  auto reduceA = [&]() {
    float s0 = 0.f, s1 = 0.f;
#pragma unroll
    for (int rr = 0; rr < 16; ++rr) {
      const int r = rb + rr;
      const int byt = r * 512 + ((cp * 2) ^ ((r & 7) << 4));
      const unsigned int wfp = *(const unsigned int*)((const char*)t_lds + byt);
      const unsigned int xjp =
          *(const unsigned int*)(h1 + (size_t)s_src[r] * 256 + cp);
      s0 += bf2f(wfp) * bf2f(xjp);
      s1 += bf2f(wfp >> 16) * bf2f(xjp >> 16);
      const int d = s_dst[r];
      if (rr == 15 || s_dst[r + 1] != d) {   // wave-uniform branch
        float* ap = agg + (size_t)d * 256 + cp;
        atomicAdd(ap, s0);
        atomicAdd(ap + 1, s1);
        s0 = 0.f; s1 = 0.f;
      }
    }
  };

  // ================= TILE A =================
  {
    const bf16x8 gA = gather_ea(eattr, perm, e0A, gr, goc);
    if (tid < 64) {
      Cs[tid]    = Cf[e0A + tid];
      s_src[tid] = srcs[e0A + tid];
      s_dst[tid] = dsts[e0A + tid];
    }
    if (tid == 64) s_dst[64] = dsts[e0B];   // e0B always < N_EDGES
    *(bf16x8*)((char*)ea_lds + gbyt) = gA;
  }
  __syncthreads();

  stage1();
  __syncthreads();        // ea_lds reads done before ep1 overwrites region
  ep1();
  __syncthreads();
  stage2();

  // ---- T14: issue tile-B gather + meta into regs (no LDS write yet);
  // latency hides under ep2(A) + reduce(A).
  const bf16x8 gB = gather_ea(eattr, perm, e0B, gr, goc);
  float cB = 0.f; int srB = 0, dB = 0, dEndB = 0;
  if (tid < 64) {
    cB  = Cf[e0B + tid];
    srB = srcs[e0B + tid];
    dB  = dsts[e0B + tid];
  }
  if (tid == 64)
    dEndB = (e0B + 64 < N_EDGES) ? dsts[e0B + 64] : -1;

  __syncthreads();        // stage-2 t_lds reads complete before ep2 overwrite
  ep2();
  __syncthreads();
  reduceA();
  __syncthreads();        // all t_lds/meta reads done; safe to overwrite

  // ================= TILE B =================
  {
    if (tid < 64) {
      Cs[tid]    = cB;
      s_src[tid] = srB;
      s_dst[tid] = dB;
    }
    if (tid == 64) s_dst[64] = dEndB;
    *(bf16x8*)((char*)ea_lds + gbyt) = gB;
  }
  __syncthreads();

  stage1();
  __syncthreads();
  ep1();
  __syncthreads();
  stage2();
  __syncthreads();
  ep2();
  __syncthreads();
  reduceA();
}

// ---------------------------------------------------------------------------
// Transpose + downcast weights
// ---------------------------------------------------------------------------
__global__ __launch_bounds__(256) void prep_weights(
    const float* __restrict__ aw, const float* __restrict__ m1,
    const float* __restrict__ m2, const float* __restrict__ o1,
    const float* __restrict__ o2,
    unsigned short* __restrict__ awt, unsigned short* __restrict__ m1t,
    unsigned short* __restrict__ m2t, unsigned short* __restrict__ o1t,
    unsigned short* __restrict__ o2t)
{
  const int i = (int)blockIdx.x * 256 + (int)threadIdx.x;
  const int c = i >> 8, k = i & 255;
  const int src = k * 256 + c;
  awt[i] = f2bf(aw[src]);
  m2t[i] = f2bf(m2[src]);
  o1t[i] = f2bf(o1[src]);
  o2t[i] = f2bf(o2[src]);
  if (k < 64) m1t[c * 64 + k] = (k < 50) ? f2bf(m1[k * 256 + c]) : (unsigned short)0;
}

extern "C" void kernel_launch(void* const* d_in, const int* in_sizes, int n_in,
                              void* d_out, int out_size, void* d_ws, size_t ws_size,
                              hipStream_t stream)
{
  const float* h    = (const float*)d_in[0];
  const int*   eidx = (const int*)d_in[1];
  const float* ew   = (const float*)d_in[2];
  const float* ea   = (const float*)d_in[3];
  const float* awW  = (const float*)d_in[4];
  const float* awb  = (const float*)d_in[5];
  const float* m1W  = (const float*)d_in[6];
  const float* m1b  = (const float*)d_in[7];
  const float* m2W  = (const float*)d_in[8];
  const float* m2b  = (const float*)d_in[9];
  const float* o1W  = (const float*)d_in[10];
  const float* o1b  = (const float*)d_in[11];
  const float* o2W  = (const float*)d_in[12];
  const float* o2b  = (const float*)d_in[13];

  char* ws = (char*)d_ws;
  unsigned short* h1  = (unsigned short*)ws;                  // 25,600,000
  float*          agg = (float*)(ws + 25600000);              // 51,200,000
  char* wbase = ws + 25600000 + 51200000;                     // 76,800,000
  unsigned short* awt = (unsigned short*)wbase;               // 131072
  unsigned short* m2t = awt + 65536;                          // 131072
  unsigned short* o1t = m2t + 65536;                          // 131072
  unsigned short* o2t = o1t + 65536;                          // 131072
  unsigned short* m1t = o2t + 65536;                          // 32768
  char* p0 = wbase + 4 * 131072 + 32768;                      // 77,357,056
  int* cnt    = (int*)p0;                                     // 200,000
  int* cursor = cnt + N_NODES;                                // 200,000
  int* perm   = cursor + N_NODES;                             // 3,200,000
  char* p1 = p0 + 400000 + 3200000;                           // 80,957,056
  float* Cf   = (float*)p1;                                   // 3,200,000
  int*   srcs = (int*)(p1 + 3200000);                         // 3,200,000
  int*   dsts = (int*)(p1 + 6400000);                         // 3,200,000

  hipMemsetAsync(agg, 0, (size_t)N_NODES * 256 * 4, stream);
  hipMemsetAsync(cnt, 0, (size_t)N_NODES * 4, stream);

  prep_weights<<<256, 256, 0, stream>>>(awW, m1W, m2W, o1W, o2W,
                                        awt, m1t, m2t, o1t, o2t);
  hist_dst<<<N_EDGES / 256, 256, 0, stream>>>(eidx, cnt);
  scan_cnt<<<1, 1024, 0, stream>>>(cnt, cursor);
  scatter_perm<<<N_EDGES / 256, 256, 0, stream>>>(eidx, ew, cursor, perm,
                                                  Cf, srcs, dsts);

  // h1 = h @ aw_W + aw_b  (bf16 out)
  gemm512<1, 0, 0><<<(N_NODES + 63) / 64, 512, 0, stream>>>(h, awt, awb, h1, N_NODES);

  // fused edge MLP + CFConv aggregation (2 tiles/block, T14 staged gather)
  edge_fused512<<<N_EDGES / 128, 512, 0, stream>>>(
      ea, perm, Cf, srcs, dsts, m1t, m1b, m2t, m2b, h1, agg);

  // out = ssp(agg @ o1 + b1) @ o2 + b2   (fused, o never leaves LDS)
  out_fused512<<<(N_NODES + 63) / 64, 512, 0, stream>>>(
      agg, o1t, o1b, o2t, o2b, (float*)d_out, N_NODES);
}

// Round 16
// 688.834 us; speedup vs baseline: 1.4523x; 1.4523x over previous
//
#include <hip/hip_runtime.h>

#define N_NODES 50000
#define N_EDGES 800000

typedef __attribute__((ext_vector_type(8))) short bf16x8;
typedef __attribute__((ext_vector_type(4))) float f32x4;
typedef __attribute__((ext_vector_type(2))) float f32x2;
typedef __attribute__((ext_vector_type(4))) unsigned int u32x4;

__device__ __forceinline__ float bf2f(unsigned int u) {
  union { unsigned int u; float f; } c; c.u = (u & 0xffffu) << 16; return c.f;
}
__device__ __forceinline__ unsigned short f2bf(float f) {
  union { float f; unsigned int u; } c; c.f = f;
  return (unsigned short)((c.u + 0x8000u) >> 16);
}
// RNE packed f32x2 -> 2xbf16 in one VALU op
__device__ __forceinline__ unsigned int pk_bf16(float lo, float hi) {
  unsigned int r;
  asm("v_cvt_pk_bf16_f32 %0, %1, %2" : "=v"(r) : "v"(lo), "v"(hi));
  return r;
}

#if __has_builtin(__builtin_amdgcn_exp2f) && __has_builtin(__builtin_amdgcn_logf)
__device__ __forceinline__ float sspf(float x) {
  const float e = __builtin_amdgcn_exp2f(fabsf(x) * -1.44269504088896f);
  const float l = __builtin_amdgcn_logf(1.0f + e);
  return fmaf(0.69314718055994531f, l, fmaxf(x, 0.0f) - 0.69314718055994531f);
}
#else
__device__ __forceinline__ float sspf(float x) {
  return fmaxf(x, 0.0f) + __logf(1.0f + __expf(-fabsf(x))) - 0.69314718055994531f;
}
#endif

__device__ __forceinline__ f32x4 MFMA(bf16x8 a, bf16x8 b, f32x4 c) {
  return __builtin_amdgcn_mfma_f32_16x16x32_bf16(a, b, c, 0, 0, 0);
}
__device__ __forceinline__ f32x4 f4bcast(float v) {
  f32x4 z = {v, v, v, v}; return z;
}

__device__ __forceinline__ bf16x8 cvt8pk(const float* __restrict__ p) {
  f32x4 x0 = *(const f32x4*)p;
  f32x4 x1 = *(const f32x4*)(p + 4);
  union { u32x4 u; bf16x8 v; } r;
  r.u[0] = pk_bf16(x0[0], x0[1]);
  r.u[1] = pk_bf16(x0[2], x0[3]);
  r.u[2] = pk_bf16(x1[0], x1[1]);
  r.u[3] = pk_bf16(x1[2], x1[3]);
  return r.v;
}

// ---------------------------------------------------------------------------
// Node GEMM: Out[M,256] = act(A@W + bias). 512 thr / 8 waves, wave owns 32
// cols. A staged once to swizzled bf16 LDS. Bias pre-loaded into acc.
// ---------------------------------------------------------------------------
template<int ADT, int ACT, int ODT>
__global__ __launch_bounds__(512, 8) void gemm512(
    const void* __restrict__ Av, const unsigned short* __restrict__ Wt,
    const float* __restrict__ bias, void* __restrict__ Outv, int M)
{
  __shared__ unsigned short a_lds[64 * 256];  // 32 KiB, swizzled
  const int m0  = (int)blockIdx.x * 64;
  const int tid = (int)threadIdx.x;

  {
    const int r   = tid >> 3;
    const int oc8 = tid & 7;
    int row = m0 + r;
    if (row >= M) row = M - 1;
    if (ADT == 1) {
      const float* ap = (const float*)Av + (size_t)row * 256 + oc8 * 32;
#pragma unroll
      for (int q = 0; q < 4; ++q) {
        const bf16x8 v = cvt8pk(ap + q * 8);
        const int byt = r * 512 + ((oc8 * 64 + q * 16) ^ ((r & 7) << 4));
        *(bf16x8*)((char*)a_lds + byt) = v;
      }
    } else {
      const unsigned short* ap =
          (const unsigned short*)Av + (size_t)row * 256 + oc8 * 32;
#pragma unroll
      for (int q = 0; q < 4; ++q) {
        const bf16x8 v = *(const bf16x8*)(ap + q * 8);
        const int byt = r * 512 + ((oc8 * 64 + q * 16) ^ ((r & 7) << 4));
        *(bf16x8*)((char*)a_lds + byt) = v;
      }
    }
  }
  __syncthreads();

  const int w  = tid >> 6, l = tid & 63, lr = l & 15, g = l >> 4;
  const int c0 = w * 32;
  const int P45 = (lr & 3) << 4;
  const int P6  = (lr & 4) << 4;
  const int alb = lr * 512 + ((g * 16) ^ P45);

  const float bs0 = bias[c0 + lr];
  const float bs1 = bias[c0 + 16 + lr];
  f32x4 acc[4][2];
#pragma unroll
  for (int a = 0; a < 4; ++a) {
    acc[a][0] = f4bcast(bs0);
    acc[a][1] = f4bcast(bs1);
  }

#pragma unroll
  for (int ks = 0; ks < 8; ++ks) {
    const int kb = ks * 32 + g * 8;
    const bf16x8 bfr0 = *(const bf16x8*)(Wt + (size_t)(c0 + lr) * 256 + kb);
    const bf16x8 bfr1 = *(const bf16x8*)(Wt + (size_t)(c0 + 16 + lr) * 256 + kb);
    const char* abase = (const char*)a_lds + (alb + ((ks * 64) ^ P6));
#pragma unroll
    for (int mf = 0; mf < 4; ++mf) {
      const bf16x8 af = *(const bf16x8*)(abase + mf * 8192);
      __builtin_amdgcn_s_setprio(1);
      acc[mf][0] = MFMA(af, bfr0, acc[mf][0]);
      acc[mf][1] = MFMA(af, bfr1, acc[mf][1]);
      __builtin_amdgcn_s_setprio(0);
    }
  }

#pragma unroll
  for (int nf = 0; nf < 2; ++nf) {
    const int col = c0 + nf * 16 + lr;
#pragma unroll
    for (int mf = 0; mf < 4; ++mf) {
#pragma unroll
      for (int i = 0; i < 4; ++i) {
        const int row = m0 + mf * 16 + g * 4 + i;
        if (row < M) {
          float x = acc[mf][nf][i];
          if (ACT) x = sspf(x);
          if (ODT == 0)
            ((unsigned short*)Outv)[(size_t)row * 256 + col] = f2bf(x);
          else
            ((float*)Outv)[(size_t)row * 256 + col] = x;
        }
      }
    }
  }
}

// ---------------------------------------------------------------------------
// Fused output MLP: out = ssp(agg@o1+b1)@o2+b2. Two K=256 stages on one
// 64-row tile; intermediate never leaves LDS.
// ---------------------------------------------------------------------------
__global__ __launch_bounds__(512, 8) void out_fused512(
    const float* __restrict__ agg,
    const unsigned short* __restrict__ o1t, const float* __restrict__ o1b,
    const unsigned short* __restrict__ o2t, const float* __restrict__ o2b,
    float* __restrict__ Out, int M)
{
  __shared__ unsigned short t_lds[64 * 256];  // 32 KiB; agg-tile, then o-tile
  const int m0  = (int)blockIdx.x * 64;
  const int tid = (int)threadIdx.x;

  // phase 0: stage agg -> bf16 swizzled LDS
  {
    const int r   = tid >> 3;
    const int oc8 = tid & 7;
    int row = m0 + r;
    if (row >= M) row = M - 1;
    const float* ap = agg + (size_t)row * 256 + oc8 * 32;
#pragma unroll
    for (int q = 0; q < 4; ++q) {
      const bf16x8 v = cvt8pk(ap + q * 8);
      const int byt = r * 512 + ((oc8 * 64 + q * 16) ^ ((r & 7) << 4));
      *(bf16x8*)((char*)t_lds + byt) = v;
    }
  }
  __syncthreads();

  const int w  = tid >> 6, l = tid & 63, lr = l & 15, g = l >> 4;
  const int c0 = w * 32;
  const int P45 = (lr & 3) << 4;
  const int P6  = (lr & 4) << 4;
  const int alb = lr * 512 + ((g * 16) ^ P45);

  f32x4 acc[4][2];
  {
    const float b0 = o1b[c0 + lr];
    const float b1 = o1b[c0 + 16 + lr];
#pragma unroll
    for (int a = 0; a < 4; ++a) {
      acc[a][0] = f4bcast(b0);
      acc[a][1] = f4bcast(b1);
    }
  }

  // stage 1: K=256 with o1
#pragma unroll
  for (int ks = 0; ks < 8; ++ks) {
    const int kb = ks * 32 + g * 8;
    const bf16x8 bfr0 = *(const bf16x8*)(o1t + (size_t)(c0 + lr) * 256 + kb);
    const bf16x8 bfr1 = *(const bf16x8*)(o1t + (size_t)(c0 + 16 + lr) * 256 + kb);
    const char* abase = (const char*)t_lds + (alb + ((ks * 64) ^ P6));
#pragma unroll
    for (int mf = 0; mf < 4; ++mf) {
      const bf16x8 af = *(const bf16x8*)(abase + mf * 8192);
      __builtin_amdgcn_s_setprio(1);
      acc[mf][0] = MFMA(af, bfr0, acc[mf][0]);
      acc[mf][1] = MFMA(af, bfr1, acc[mf][1]);
      __builtin_amdgcn_s_setprio(0);
    }
  }
  __syncthreads();   // stage-1 reads done before overwrite

  // epilogue 1: o = ssp(acc) -> t_lds (cvt_pk)
#pragma unroll
  for (int nf = 0; nf < 2; ++nf) {
    const int colb = (c0 + nf * 16 + lr) * 2;
#pragma unroll
    for (int i = 0; i < 4; ++i) {
      const int gi = g * 4 + i;
      char* wp = (char*)t_lds + (gi * 512 + (colb ^ ((gi & 7) << 4)));
      const float v0 = sspf(acc[0][nf][i]);
      const float v1 = sspf(acc[1][nf][i]);
      const float v2 = sspf(acc[2][nf][i]);
      const float v3 = sspf(acc[3][nf][i]);
      const unsigned int p01 = pk_bf16(v0, v1);
      const unsigned int p23 = pk_bf16(v2, v3);
      *(unsigned short*)(wp)         = (unsigned short)p01;
      *(unsigned short*)(wp + 8192)  = (unsigned short)(p01 >> 16);
      *(unsigned short*)(wp + 16384) = (unsigned short)p23;
      *(unsigned short*)(wp + 24576) = (unsigned short)(p23 >> 16);
    }
  }
  __syncthreads();

  // stage 2: K=256 with o2
  {
    const float b0 = o2b[c0 + lr];
    const float b1 = o2b[c0 + 16 + lr];
#pragma unroll
    for (int a = 0; a < 4; ++a) {
      acc[a][0] = f4bcast(b0);
      acc[a][1] = f4bcast(b1);
    }
  }
#pragma unroll
  for (int ks = 0; ks < 8; ++ks) {
    const int kb = ks * 32 + g * 8;
    const bf16x8 bfr0 = *(const bf16x8*)(o2t + (size_t)(c0 + lr) * 256 + kb);
    const bf16x8 bfr1 = *(const bf16x8*)(o2t + (size_t)(c0 + 16 + lr) * 256 + kb);
    const char* abase = (const char*)t_lds + (alb + ((ks * 64) ^ P6));
#pragma unroll
    for (int mf = 0; mf < 4; ++mf) {
      const bf16x8 af = *(const bf16x8*)(abase + mf * 8192);
      __builtin_amdgcn_s_setprio(1);
      acc[mf][0] = MFMA(af, bfr0, acc[mf][0]);
      acc[mf][1] = MFMA(af, bfr1, acc[mf][1]);
      __builtin_amdgcn_s_setprio(0);
    }
  }

  // epilogue: f32 store
#pragma unroll
  for (int nf = 0; nf < 2; ++nf) {
    const int col = c0 + nf * 16 + lr;
#pragma unroll
    for (int mf = 0; mf < 4; ++mf) {
#pragma unroll
      for (int i = 0; i < 4; ++i) {
        const int row = m0 + mf * 16 + g * 4 + i;
        if (row < M)
          Out[(size_t)row * 256 + col] = acc[mf][nf][i];
      }
    }
  }
}

// ---------------------------------------------------------------------------
// Counting sort by dst.
// ---------------------------------------------------------------------------
__global__ __launch_bounds__(256) void hist_dst(const int* __restrict__ eidx,
                                                int* __restrict__ cnt)
{
  const int e = (int)blockIdx.x * 256 + (int)threadIdx.x;
  atomicAdd(&cnt[eidx[N_EDGES + e]], 1);
}

__global__ __launch_bounds__(1024) void scan_cnt(const int* __restrict__ cnt,
                                                 int* __restrict__ cursor)
{
  __shared__ int part[1024];
  const int t = (int)threadIdx.x;
  const int base = t * 49;
  int s = 0;
#pragma unroll 7
  for (int j = 0; j < 49; ++j) {
    const int idx = base + j;
    if (idx < N_NODES) s += cnt[idx];
  }
  part[t] = s;
  __syncthreads();
  for (int off = 1; off < 1024; off <<= 1) {
    int v = 0;
    if (t >= off) v = part[t - off];
    __syncthreads();
    part[t] += v;
    __syncthreads();
  }
  int run = (t == 0) ? 0 : part[t - 1];
#pragma unroll 7
  for (int j = 0; j < 49; ++j) {
    const int idx = base + j;
    if (idx < N_NODES) { cursor[idx] = run; run += cnt[idx]; }
  }
}

__global__ __launch_bounds__(256) void scatter_perm(
    const int* __restrict__ eidx, const float* __restrict__ ew,
    int* __restrict__ cursor, int* __restrict__ perm,
    float* __restrict__ Cf, int* __restrict__ srcs, int* __restrict__ dsts)
{
  const int e = (int)blockIdx.x * 256 + (int)threadIdx.x;
  const int d = eidx[N_EDGES + e];
  const int pos = atomicAdd(&cursor[d], 1);
  perm[pos] = e;
  Cf[pos]   = 0.5f * (__cosf(ew[e] * 0.31415926535897931f) + 1.0f);
  srcs[pos] = eidx[e];
  dsts[pos] = d;
}

// ---------------------------------------------------------------------------
// FUSED edge pipeline over dst-SORTED edges. 64 edges/block, 512 thr (8
// waves, wave owns 32 cols). Direct eattr[perm] gather -> swizzled LDS.
// Bias in acc; cvt_pk epilogues; Wf never leaves LDS. Reduce = R10/R12 form:
// interleaved h1 gather + pure atomics. (R11 preload, R13 XCD swizzle, R14
// plain-store, R15 2-tile reg-staging: all null/negative — do not revisit.)
// ---------------------------------------------------------------------------
__global__ __launch_bounds__(512, 8) void edge_fused512(
    const float* __restrict__ eattr, const int* __restrict__ perm,
    const float* __restrict__ Cf,
    const int* __restrict__ srcs, const int* __restrict__ dsts,
    const unsigned short* __restrict__ m1t, const float* __restrict__ m1b,
    const unsigned short* __restrict__ m2t, const float* __restrict__ m2b,
    const unsigned short* __restrict__ h1, float* __restrict__ agg)
{
  __shared__ unsigned short t_lds[64 * 256];  // 32 KiB; ea-tile, t, then Wf
  __shared__ float Cs[64];
  __shared__ int s_src[64];
  __shared__ int s_dst[65];
  unsigned short* ea_lds = t_lds;             // [64 rows][128B] alias (8 KiB)

  const int e0  = (int)blockIdx.x * 64;
  const int tid = (int)threadIdx.x;

  // ---- phase 0: gather eattr[perm[e0+r]] -> bf16 ea_lds (swizzled) + meta
  {
    const int r  = tid >> 3;
    const int oc = tid & 7;
    const int p  = perm[e0 + r];
    const float* ap = eattr + (size_t)p * 50 + oc * 8;
    union { u32x4 u; bf16x8 v; } t;
    if (oc < 6) {
      f32x2 a0 = *(const f32x2*)(ap);
      f32x2 a1 = *(const f32x2*)(ap + 2);
      f32x2 a2 = *(const f32x2*)(ap + 4);
      f32x2 a3 = *(const f32x2*)(ap + 6);
      t.u[0] = pk_bf16(a0[0], a0[1]);
      t.u[1] = pk_bf16(a1[0], a1[1]);
      t.u[2] = pk_bf16(a2[0], a2[1]);
      t.u[3] = pk_bf16(a3[0], a3[1]);
    } else if (oc == 6) {
      f32x2 a0 = *(const f32x2*)(ap);
      t.u[0] = pk_bf16(a0[0], a0[1]);
      t.u[1] = 0; t.u[2] = 0; t.u[3] = 0;
    } else {
      t.u[0] = 0; t.u[1] = 0; t.u[2] = 0; t.u[3] = 0;
    }
    const int byt = r * 128 + ((oc * 16) ^ ((r & 7) << 4));
    *(bf16x8*)((char*)ea_lds + byt) = t.v;
  }
  if (tid < 64) {
    Cs[tid]    = Cf[e0 + tid];
    s_src[tid] = srcs[e0 + tid];
    s_dst[tid] = dsts[e0 + tid];
  }
  if (tid == 64)
    s_dst[64] = (e0 + 64 < N_EDGES) ? dsts[e0 + 64] : -1;
  __syncthreads();

  const int w  = tid >> 6;
  const int l  = tid & 63;
  const int lr = l & 15;
  const int g  = l >> 4;
  const int c0 = w * 32;

  const int P45  = (lr & 3) << 4;
  const int P6   = (lr & 4) << 4;
  const int alb1 = lr * 128 + ((g * 16) ^ P45);
  const int alb2 = lr * 512 + ((g * 16) ^ P45);

  const float b10 = m1b[c0 + lr];
  const float b11 = m1b[c0 + 16 + lr];
  f32x4 acc[4][2];
#pragma unroll
  for (int a = 0; a < 4; ++a) {
    acc[a][0] = f4bcast(b10);
    acc[a][1] = f4bcast(b11);
  }

  // ---- stage 1: K=64
#pragma unroll
  for (int ks = 0; ks < 2; ++ks) {
    const int kb = ks * 32 + g * 8;
    const bf16x8 bfr0 = *(const bf16x8*)(m1t + (c0 + lr) * 64 + kb);
    const bf16x8 bfr1 = *(const bf16x8*)(m1t + (c0 + 16 + lr) * 64 + kb);
    const char* abase = (const char*)ea_lds + (alb1 + ((ks * 64) ^ P6));
#pragma unroll
    for (int mf = 0; mf < 4; ++mf) {
      const bf16x8 af = *(const bf16x8*)(abase + mf * 2048);
      __builtin_amdgcn_s_setprio(1);
      acc[mf][0] = MFMA(af, bfr0, acc[mf][0]);
      acc[mf][1] = MFMA(af, bfr1, acc[mf][1]);
      __builtin_amdgcn_s_setprio(0);
    }
  }
  __syncthreads();

  // ---- epilogue 1: t = ssp(.) -> t_lds
#pragma unroll
  for (int nf = 0; nf < 2; ++nf) {
    const int colb = (c0 + nf * 16 + lr) * 2;
#pragma unroll
    for (int i = 0; i < 4; ++i) {
      const int gi = g * 4 + i;
      char* wp = (char*)t_lds + (gi * 512 + (colb ^ ((gi & 7) << 4)));
      const float v0 = sspf(acc[0][nf][i]);
      const float v1 = sspf(acc[1][nf][i]);
      const float v2 = sspf(acc[2][nf][i]);
      const float v3 = sspf(acc[3][nf][i]);
      const unsigned int p01 = pk_bf16(v0, v1);
      const unsigned int p23 = pk_bf16(v2, v3);
      *(unsigned short*)(wp)         = (unsigned short)p01;
      *(unsigned short*)(wp + 8192)  = (unsigned short)(p01 >> 16);
      *(unsigned short*)(wp + 16384) = (unsigned short)p23;
      *(unsigned short*)(wp + 24576) = (unsigned short)(p23 >> 16);
    }
  }
  __syncthreads();

  // ---- stage 2: K=256
  const float b20 = m2b[c0 + lr];
  const float b21 = m2b[c0 + 16 + lr];
#pragma unroll
  for (int a = 0; a < 4; ++a) {
    acc[a][0] = f4bcast(b20);
    acc[a][1] = f4bcast(b21);
  }

#pragma unroll
  for (int ks = 0; ks < 8; ++ks) {
    const int kb = ks * 32 + g * 8;
    const bf16x8 bfr0 = *(const bf16x8*)(m2t + (size_t)(c0 + lr) * 256 + kb);
    const bf16x8 bfr1 = *(const bf16x8*)(m2t + (size_t)(c0 + 16 + lr) * 256 + kb);
    const char* abase = (const char*)t_lds + (alb2 + ((ks * 64) ^ P6));
#pragma unroll
    for (int mf = 0; mf < 4; ++mf) {
      const bf16x8 af = *(const bf16x8*)(abase + mf * 8192);
      __builtin_amdgcn_s_setprio(1);
      acc[mf][0] = MFMA(af, bfr0, acc[mf][0]);
      acc[mf][1] = MFMA(af, bfr1, acc[mf][1]);
      __builtin_amdgcn_s_setprio(0);
    }
  }
  __syncthreads();   // stage-2 reads complete block-wide before overwrite

  // ---- epilogue 2: Wf = ssp(acc)*C -> t_lds (same swizzle, cvt_pk)
#pragma unroll
  for (int nf = 0; nf < 2; ++nf) {
    const int colb = (c0 + nf * 16 + lr) * 2;
#pragma unroll
    for (int i = 0; i < 4; ++i) {
      const int gi = g * 4 + i;
      char* wp = (char*)t_lds + (gi * 512 + (colb ^ ((gi & 7) << 4)));
      const float v0 = sspf(acc[0][nf][i]) * Cs[gi];
      const float v1 = sspf(acc[1][nf][i]) * Cs[16 + gi];
      const float v2 = sspf(acc[2][nf][i]) * Cs[32 + gi];
      const float v3 = sspf(acc[3][nf][i]) * Cs[48 + gi];
      const unsigned int p01 = pk_bf16(v0, v1);
      const unsigned int p23 = pk_bf16(v2, v3);
      *(unsigned short*)(wp)         = (unsigned short)p01;
      *(unsigned short*)(wp + 8192)  = (unsigned short)(p01 >> 16);
      *(unsigned short*)(wp + 16384) = (unsigned short)p23;
      *(unsigned short*)(wp + 24576) = (unsigned short)(p23 >> 16);
    }
  }
  __syncthreads();

  // ---- segmented reduce: quarter owns 16 rows; thread owns col pair;
  // interleaved h1 gather; pure atomics.
  {
    const int q2 = tid >> 7;                 // 0..3
    const int cp = (tid & 127) * 2;          // even column
    const int rb = q2 * 16;
    float s0 = 0.f, s1 = 0.f;
#pragma unroll
    for (int rr = 0; rr < 16; ++rr) {
      const int r = rb + rr;
      const int byt = r * 512 + ((cp * 2) ^ ((r & 7) << 4));
      const unsigned int wfp = *(const unsigned int*)((const char*)t_lds + byt);
      const unsigned int xjp =
          *(const unsigned int*)(h1 + (size_t)s_src[r] * 256 + cp);
      s0 += bf2f(wfp) * bf2f(xjp);
      s1 += bf2f(wfp >> 16) * bf2f(xjp >> 16);
      const int d = s_dst[r];
      if (rr == 15 || s_dst[r + 1] != d) {   // wave-uniform branch
        float* ap = agg + (size_t)d * 256 + cp;
        atomicAdd(ap, s0);
        atomicAdd(ap + 1, s1);
        s0 = 0.f; s1 = 0.f;
      }
    }
  }
}

// ---------------------------------------------------------------------------
// Transpose + downcast weights
// ---------------------------------------------------------------------------
__global__ __launch_bounds__(256) void prep_weights(
    const float* __restrict__ aw, const float* __restrict__ m1,
    const float* __restrict__ m2, const float* __restrict__ o1,
    const float* __restrict__ o2,
    unsigned short* __restrict__ awt, unsigned short* __restrict__ m1t,
    unsigned short* __restrict__ m2t, unsigned short* __restrict__ o1t,
    unsigned short* __restrict__ o2t)
{
  const int i = (int)blockIdx.x * 256 + (int)threadIdx.x;
  const int c = i >> 8, k = i & 255;
  const int src = k * 256 + c;
  awt[i] = f2bf(aw[src]);
  m2t[i] = f2bf(m2[src]);
  o1t[i] = f2bf(o1[src]);
  o2t[i] = f2bf(o2[src]);
  if (k < 64) m1t[c * 64 + k] = (k < 50) ? f2bf(m1[k * 256 + c]) : (unsigned short)0;
}

extern "C" void kernel_launch(void* const* d_in, const int* in_sizes, int n_in,
                              void* d_out, int out_size, void* d_ws, size_t ws_size,
                              hipStream_t stream)
{
  const float* h    = (const float*)d_in[0];
  const int*   eidx = (const int*)d_in[1];
  const float* ew   = (const float*)d_in[2];
  const float* ea   = (const float*)d_in[3];
  const float* awW  = (const float*)d_in[4];
  const float* awb  = (const float*)d_in[5];
  const float* m1W  = (const float*)d_in[6];
  const float* m1b  = (const float*)d_in[7];
  const float* m2W  = (const float*)d_in[8];
  const float* m2b  = (const float*)d_in[9];
  const float* o1W  = (const float*)d_in[10];
  const float* o1b  = (const float*)d_in[11];
  const float* o2W  = (const float*)d_in[12];
  const float* o2b  = (const float*)d_in[13];

  char* ws = (char*)d_ws;
  unsigned short* h1  = (unsigned short*)ws;                  // 25,600,000
  float*          agg = (float*)(ws + 25600000);              // 51,200,000
  char* wbase = ws + 25600000 + 51200000;                     // 76,800,000
  unsigned short* awt = (unsigned short*)wbase;               // 131072
  unsigned short* m2t = awt + 65536;                          // 131072
  unsigned short* o1t = m2t + 65536;                          // 131072
  unsigned short* o2t = o1t + 65536;                          // 131072
  unsigned short* m1t = o2t + 65536;                          // 32768
  char* p0 = wbase + 4 * 131072 + 32768;                      // 77,357,056
  int* cnt    = (int*)p0;                                     // 200,000
  int* cursor = cnt + N_NODES;                                // 200,000
  int* perm   = cursor + N_NODES;                             // 3,200,000
  char* p1 = p0 + 400000 + 3200000;                           // 80,957,056
  float* Cf   = (float*)p1;                                   // 3,200,000
  int*   srcs = (int*)(p1 + 3200000);                         // 3,200,000
  int*   dsts = (int*)(p1 + 6400000);                         // 3,200,000

  hipMemsetAsync(agg, 0, (size_t)N_NODES * 256 * 4, stream);
  hipMemsetAsync(cnt, 0, (size_t)N_NODES * 4, stream);

  prep_weights<<<256, 256, 0, stream>>>(awW, m1W, m2W, o1W, o2W,
                                        awt, m1t, m2t, o1t, o2t);
  hist_dst<<<N_EDGES / 256, 256, 0, stream>>>(eidx, cnt);
  scan_cnt<<<1, 1024, 0, stream>>>(cnt, cursor);
  scatter_perm<<<N_EDGES / 256, 256, 0, stream>>>(eidx, ew, cursor, perm,
                                                  Cf, srcs, dsts);

  // h1 = h @ aw_W + aw_b  (bf16 out)
  gemm512<1, 0, 0><<<(N_NODES + 63) / 64, 512, 0, stream>>>(h, awt, awb, h1, N_NODES);

  // fused edge MLP + CFConv aggregation
  edge_fused512<<<N_EDGES / 64, 512, 0, stream>>>(
      ea, perm, Cf, srcs, dsts, m1t, m1b, m2t, m2b, h1, agg);

  // out = ssp(agg @ o1 + b1) @ o2 + b2   (fused, o never leaves LDS)
  out_fused512<<<(N_NODES + 63) / 64, 512, 0, stream>>>(
      agg, o1t, o1b, o2t, o2b, (float*)d_out, N_NODES);
}